// Round 1
// baseline (25.018 us; speedup 1.0000x reference)
//
#include <hip/hip_runtime.h>

// Problem constants (from reference): B=16, C=5, H=512, W=512
constexpr int Bn   = 16;
constexpr int Cn   = 5;
constexpr int HW   = 512 * 512;       // 262144
constexpr int HW4  = HW / 4;          // 65536 float4 groups per (b, c) plane
constexpr int NVEC = Bn * HW / 4;     // 1,048,576 4-pixel work items
constexpr int NBLK = 2048;            // partial-sum blocks
constexpr float SCALE = 1.0f / (float)(Bn * HW);   // 1 / n_pix

__device__ __forceinline__ float block_reduce_256(float v) {
    // 64-lane wave shuffle reduce, then 4-wave LDS combine (deterministic tree)
    #pragma unroll
    for (int off = 32; off > 0; off >>= 1)
        v += __shfl_down(v, off, 64);
    __shared__ float s[4];
    const int lane = threadIdx.x & 63;
    const int wid  = threadIdx.x >> 6;
    if (lane == 0) s[wid] = v;
    __syncthreads();
    if (threadIdx.x == 0) v = (s[0] + s[1]) + (s[2] + s[3]);
    return v;
}

__device__ __forceinline__ float pixel_pen(float l0, float l1, float l2, float l3,
                                           float l4, int t) {
    // softmax over 5 channels; penalties computed on unnormalized exps,
    // single divide by the partition sum at the end (relu(x)/S == relu(x/S), S>0).
    float m  = fmaxf(fmaxf(fmaxf(l0, l1), fmaxf(l2, l3)), l4);
    float e0 = __expf(l0 - m);
    float e1 = __expf(l1 - m);
    float e2 = __expf(l2 - m);
    float e3 = __expf(l3 - m);
    float e4 = __expf(l4 - m);
    float S  = ((e0 + e1) + (e2 + e3)) + e4;
    float d1 = e1 - e0;
    float d2 = e2 - e1;
    float d3 = e3 - e2;
    float d4 = e4 - e3;
    float pen = 0.0f;
    pen += (t >= 1) ? fmaxf(-d1, 0.0f) : fmaxf(d1, 0.0f);
    pen += (t >= 2) ? fmaxf(-d2, 0.0f) : fmaxf(d2, 0.0f);
    pen += (t >= 3) ? fmaxf(-d3, 0.0f) : fmaxf(d3, 0.0f);
    pen += (t >= 4) ? fmaxf(-d4, 0.0f) : fmaxf(d4, 0.0f);
    return pen / S;
}

__global__ void __launch_bounds__(256)
o2_loss_partial(const float4* __restrict__ pred,   // (B, 5, H, W) as float4
                const int4*  __restrict__ lab,     // (B, H, W) as int4
                float* __restrict__ partial) {
    float acc = 0.0f;
    const int stride = gridDim.x * 256;
    for (int v = blockIdx.x * 256 + threadIdx.x; v < NVEC; v += stride) {
        const int b   = v >> 16;        // v / HW4
        const int hw4 = v & (HW4 - 1);  // v % HW4
        const float4* base = pred + (size_t)b * (Cn * HW4) + hw4;
        float4 x0 = base[0 * HW4];
        float4 x1 = base[1 * HW4];
        float4 x2 = base[2 * HW4];
        float4 x3 = base[3 * HW4];
        float4 x4 = base[4 * HW4];
        int4   t  = lab[v];
        acc += pixel_pen(x0.x, x1.x, x2.x, x3.x, x4.x, t.x);
        acc += pixel_pen(x0.y, x1.y, x2.y, x3.y, x4.y, t.y);
        acc += pixel_pen(x0.z, x1.z, x2.z, x3.z, x4.z, t.z);
        acc += pixel_pen(x0.w, x1.w, x2.w, x3.w, x4.w, t.w);
    }
    acc = block_reduce_256(acc);
    if (threadIdx.x == 0) partial[blockIdx.x] = acc;
}

__global__ void __launch_bounds__(256)
o2_loss_finalize(const float* __restrict__ partial, float* __restrict__ out) {
    float v = 0.0f;
    for (int i = threadIdx.x; i < NBLK; i += 256)
        v += partial[i];
    v = block_reduce_256(v);
    if (threadIdx.x == 0) out[0] = v * SCALE;
}

extern "C" void kernel_launch(void* const* d_in, const int* in_sizes, int n_in,
                              void* d_out, int out_size, void* d_ws, size_t ws_size,
                              hipStream_t stream) {
    const float4* pred = (const float4*)d_in[0];
    const int4*   lab  = (const int4*)d_in[1];
    float* partial = (float*)d_ws;          // NBLK floats = 8 KB scratch
    float* out     = (float*)d_out;

    o2_loss_partial<<<NBLK, 256, 0, stream>>>(pred, lab, partial);
    o2_loss_finalize<<<1, 256, 0, stream>>>(partial, out);
}